// Round 5
// baseline (589.980 us; speedup 1.0000x reference)
//
#include <hip/hip_runtime.h>
#include <math.h>

#define NN 768
#define CS 384
#define CZ 128
#define CH 16
#define HH 12
#define PQ 4
#define PV 8
#define OUTIN 2112

#define SC_QK 0.14433756729740643f   // sqrt(1/(3*16))
#define SC_B  0.57735026918962576f   // sqrt(1/3)
#define SC_HW 0.13608276348795434f   // sqrt(2/(27*4))

// ---------------- Kernel A: input projections (s @ W.T + b) ----------------
__global__ __launch_bounds__(256) void kproj(
    const float* __restrict__ s,
    const float* __restrict__ Wq,  const float* __restrict__ bq,
    const float* __restrict__ Wkv, const float* __restrict__ bkv,
    const float* __restrict__ Wqp, const float* __restrict__ bqp,
    const float* __restrict__ Wkvp,const float* __restrict__ bkvp,
    float* __restrict__ q, float* __restrict__ kT, float* __restrict__ vallT,
    float* __restrict__ qpr, float* __restrict__ kvpr)
{
    __shared__ float s_lds[8*384];
    int n0 = blockIdx.x * 8;
    int t = threadIdx.x;
    for (int idx = t; idx < 8*384; idx += 256)
        s_lds[idx] = s[(n0 + idx/384)*384 + (idx%384)];
    __syncthreads();

    int o = blockIdx.y * 128 + (t & 127);
    int ng = t >> 7;
    const float* wrow; float bias;
    if (o < 192)      { wrow = Wq   + o*384;       bias = bq[o]; }
    else if (o < 576) { wrow = Wkv  + (o-192)*384; bias = bkv[o-192]; }
    else if (o < 720) { wrow = Wqp  + (o-576)*384; bias = bqp[o-576]; }
    else              { wrow = Wkvp + (o-720)*384; bias = bkvp[o-720]; }

    float acc[4] = {bias, bias, bias, bias};
    const float4* wr4 = reinterpret_cast<const float4*>(wrow);
    for (int c4 = 0; c4 < 96; ++c4) {
        float4 w = wr4[c4];
        #pragma unroll
        for (int nn = 0; nn < 4; ++nn) {
            const float* sr = &s_lds[(ng*4+nn)*384 + c4*4];
            acc[nn] = fmaf(w.x, sr[0], acc[nn]);
            acc[nn] = fmaf(w.y, sr[1], acc[nn]);
            acc[nn] = fmaf(w.z, sr[2], acc[nn]);
            acc[nn] = fmaf(w.w, sr[3], acc[nn]);
        }
    }
    #pragma unroll
    for (int nn = 0; nn < 4; ++nn) {
        int n = n0 + ng*4 + nn;
        float v = acc[nn];
        if (o < 192)      q[n*192 + o] = v;
        else if (o < 576) {
            int oo = o - 192, h = oo >> 5, cc = oo & 31;
            if (cc < 16) kT[(h*NN + n)*16 + cc] = v;
            else         vallT[(size_t)(h*40 + (cc-16))*NN + n] = v;
        }
        else if (o < 720) qpr[n*144 + (o-576)] = v;
        else              kvpr[n*432 + (o-720)] = v;
    }
}

// ---------------- Kernel B: apply frames (rot, trans) to points ----------------
__global__ __launch_bounds__(192) void krot(
    const float* __restrict__ rot, const float* __restrict__ trans,
    const float* __restrict__ qpr, const float* __restrict__ kvpr,
    float* __restrict__ qp, float* __restrict__ kpT, float* __restrict__ vallT)
{
    int n = blockIdx.x;
    __shared__ float R[9], T[3];
    int t = threadIdx.x;
    if (t < 9) R[t] = rot[n*9 + t];
    if (t < 3) T[t] = trans[n*3 + t];
    __syncthreads();

    const float* src = (t < 48) ? (qpr + n*144 + t*3) : (kvpr + n*432 + (t-48)*3);
    float x = src[0], y = src[1], z = src[2];
    float wx = R[0]*x + R[1]*y + R[2]*z + T[0];
    float wy = R[3]*x + R[4]*y + R[5]*z + T[1];
    float wz = R[6]*x + R[7]*y + R[8]*z + T[2];
    if (t < 48) {
        float* d = qp + n*144 + t*3;
        d[0]=wx; d[1]=wy; d[2]=wz;
    } else {
        int pi = t - 48, h = pi/12, pp = pi%12;
        if (pp < 4) {
            float* d = kpT + (h*NN+n)*12 + pp*3;
            d[0]=wx; d[1]=wy; d[2]=wz;
        } else {
            int ch = h*40 + 16 + (pp-4)*3;
            vallT[(size_t)(ch+0)*NN + n] = wx;
            vallT[(size_t)(ch+1)*NN + n] = wy;
            vallT[(size_t)(ch+2)*NN + n] = wz;
        }
    }
}

// ---------------- Kernel C1: z-independent logit part ----------------
__global__ __launch_bounds__(256) void kqk(
    const float* __restrict__ kT, const float* __restrict__ kpT,
    const float* __restrict__ q, const float* __restrict__ qp,
    const float* __restrict__ mask, const float* __restrict__ head_w,
    const float* __restrict__ bb, float* __restrict__ lqd)
{
    const int h = blockIdx.z;
    const int j0 = blockIdx.x * 128;
    const int i0 = blockIdx.y * 32;
    __shared__ float kt_l[16][132], kp_l[12][132];
    __shared__ float q_l[32][16], qp_l[32][12];
    __shared__ float mi_l[32], mj_l[128];
    const int t = threadIdx.x;
    for (int idx = t; idx < 2048; idx += 256) {
        int j = idx >> 4, c = idx & 15;
        kt_l[c][j] = kT[(size_t)(h*NN + j0 + j)*16 + c];
    }
    for (int idx = t; idx < 1536; idx += 256) {
        int j = idx / 12, e = idx - j*12;
        kp_l[e][j] = kpT[(size_t)(h*NN + j0 + j)*12 + e];
    }
    for (int idx = t; idx < 512; idx += 256) {
        int ii = idx >> 4, c = idx & 15;
        q_l[ii][c] = q[(i0+ii)*192 + h*16 + c];
    }
    for (int idx = t; idx < 384; idx += 256) {
        int ii = idx / 12, e = idx - ii*12;
        qp_l[ii][e] = qp[(i0+ii)*144 + h*12 + e];
    }
    if (t < 32)  mi_l[t] = mask[i0 + t];
    if (t < 128) mj_l[t] = mask[j0 + t];
    const float hwh = log1pf(expf(head_w[h])) * SC_HW;
    const float bbh = bb[h];
    __syncthreads();

    const int jl = t & 127, ig = t >> 7;
    const float mj = mj_l[jl];
    #pragma unroll 4
    for (int ii = 0; ii < 16; ++ii) {
        const int il = ig*16 + ii;
        float qk = 0.f;
        #pragma unroll
        for (int c = 0; c < 16; ++c) qk = fmaf(kt_l[c][jl], q_l[il][c], qk);
        float d2 = 0.f;
        #pragma unroll
        for (int e = 0; e < 12; ++e) { float d = qp_l[il][e] - kp_l[e][jl]; d2 = fmaf(d, d, d2); }
        float mt = 1e9f * (mi_l[il]*mj - 1.0f);
        float lg = fmaf(qk, SC_QK, fmaf(-0.5f*hwh, d2, bbh)) + mt;
        lqd[((size_t)h*NN + i0 + il)*NN + j0 + jl] = lg;
    }
}

// ---------------- Kernel C2: g = lqd + SC_B*(z·Wb); track row max ----------------
// One block per row i; Wb via scalarized (readfirstlane) global loads; no softmax here.
__global__ __launch_bounds__(256, 4) void kbias(
    const float* __restrict__ z, const float* __restrict__ Wb,
    const float* __restrict__ lqd, float* __restrict__ g_out,
    float* __restrict__ mrow)
{
    __shared__ float4 zt4[64][32];         // 32 KB, physical [j][c4 ^ (j&7)]

    const int i = blockIdx.x, t = threadIdx.x;
    const int w = t >> 6, l = t & 63, h0 = w*3;
    const int h0u = __builtin_amdgcn_readfirstlane(h0);
    const float4* __restrict__ wbh = (const float4*)(Wb + h0u*CZ);   // 96 float4: 3 head rows

    const float4* __restrict__ zg = (const float4*)(z + (size_t)i*NN*CZ);
    float4 stg[8];
    #pragma unroll
    for (int k = 0; k < 8; ++k) stg[k] = zg[k*256 + t];
    #pragma unroll
    for (int k = 0; k < 8; ++k) {
        int slot = k*256 + t, j = slot >> 5, c4 = slot & 31;
        zt4[j][c4 ^ (j & 7)] = stg[k];
    }

    float m0 = -1e30f, m1 = -1e30f, m2 = -1e30f;
    const int swl = l & 7;

    for (int tile = 0; tile < 12; ++tile) {
        __syncthreads();   // staged tile visible
        if (tile + 1 < 12) {   // T14: issue next tile's loads before compute
            #pragma unroll
            for (int k = 0; k < 8; ++k) stg[k] = zg[(tile+1)*2048 + k*256 + t];
        }
        const int j = tile*64 + l;
        float lq0 = lqd[((size_t)(h0+0)*NN + i)*NN + j];
        float lq1 = lqd[((size_t)(h0+1)*NN + i)*NN + j];
        float lq2 = lqd[((size_t)(h0+2)*NN + i)*NN + j];
        float b0 = 0.f, b1 = 0.f, b2 = 0.f;
        #pragma unroll
        for (int c4 = 0; c4 < 32; ++c4) {
            float4 zv = zt4[l][c4 ^ swl];
            float4 w0 = wbh[c4];        // wave-uniform -> s_load
            float4 w1 = wbh[32 + c4];
            float4 w2 = wbh[64 + c4];
            b0 = fmaf(zv.x,w0.x,b0); b0 = fmaf(zv.y,w0.y,b0); b0 = fmaf(zv.z,w0.z,b0); b0 = fmaf(zv.w,w0.w,b0);
            b1 = fmaf(zv.x,w1.x,b1); b1 = fmaf(zv.y,w1.y,b1); b1 = fmaf(zv.z,w1.z,b1); b1 = fmaf(zv.w,w1.w,b1);
            b2 = fmaf(zv.x,w2.x,b2); b2 = fmaf(zv.y,w2.y,b2); b2 = fmaf(zv.z,w2.z,b2); b2 = fmaf(zv.w,w2.w,b2);
        }
        float g0 = fmaf(b0, SC_B, lq0);
        float g1 = fmaf(b1, SC_B, lq1);
        float g2 = fmaf(b2, SC_B, lq2);
        g_out[((size_t)(h0+0)*NN + i)*NN + j] = g0;
        g_out[((size_t)(h0+1)*NN + i)*NN + j] = g1;
        g_out[((size_t)(h0+2)*NN + i)*NN + j] = g2;
        m0 = fmaxf(m0, g0); m1 = fmaxf(m1, g1); m2 = fmaxf(m2, g2);
        __syncthreads();   // zt4 reads done
        if (tile + 1 < 12) {
            #pragma unroll
            for (int k = 0; k < 8; ++k) {
                int slot = k*256 + t, jj = slot >> 5, c4 = slot & 31;
                zt4[jj][c4 ^ (jj & 7)] = stg[k];
            }
        }
    }

    #pragma unroll
    for (int off = 32; off >= 1; off >>= 1) {
        m0 = fmaxf(m0, __shfl_xor(m0, off, 64));
        m1 = fmaxf(m1, __shfl_xor(m1, off, 64));
        m2 = fmaxf(m2, __shfl_xor(m2, off, 64));
    }
    if (l == 0) {
        mrow[(h0+0)*NN + i] = m0;
        mrow[(h0+1)*NN + i] = m1;
        mrow[(h0+2)*NN + i] = m2;
    }
}

// ---------------- Kernel C3: o_pair = softmax(g) @ z ----------------
// One block per row i. Stage p=exp(g-m) into LDS + block-reduce sums,
// then matvec with 2-rows-per-wave float4 z loads and xor(32) end-reduce.
__global__ __launch_bounds__(256, 4) void kopair(
    const float* __restrict__ z, const float* __restrict__ g,
    const float* __restrict__ mrow, float* __restrict__ cat)
{
    __shared__ float an_l[12][776];
    __shared__ float sred[12][4];
    __shared__ float sinv[12];
    const int i = blockIdx.x, t = threadIdx.x, w = t >> 6, l = t & 63;

    float ps[12];
    #pragma unroll
    for (int h = 0; h < 12; ++h) ps[h] = 0.f;
    #pragma unroll
    for (int h = 0; h < 12; ++h) {
        const float mh = mrow[h*NN + i];
        const float* gr = g + ((size_t)h*NN + i)*NN;
        #pragma unroll
        for (int k = 0; k < 3; ++k) {
            int j = k*256 + t;
            float p = __expf(gr[j] - mh);
            an_l[h][j] = p;
            ps[h] += p;
        }
    }
    #pragma unroll
    for (int h = 0; h < 12; ++h) {
        float s = ps[h];
        #pragma unroll
        for (int off = 32; off >= 1; off >>= 1) s += __shfl_xor(s, off, 64);
        if (l == 0) sred[h][w] = s;
    }
    __syncthreads();
    if (t < 12) sinv[t] = 1.0f / (sred[t][0] + sred[t][1] + sred[t][2] + sred[t][3]);
    __syncthreads();

    const int h0 = w*3, jo = l >> 5, c4 = l & 31;
    const float4* __restrict__ zr = (const float4*)(z + (size_t)i*NN*CZ);
    float a0x=0,a0y=0,a0z=0,a0w=0, a1x=0,a1y=0,a1z=0,a1w=0, a2x=0,a2y=0,a2z=0,a2w=0;
    #pragma unroll 4
    for (int jb = 0; jb < 384; ++jb) {
        const int j = jb*2 + jo;
        float4 zv = zr[(size_t)j*32 + c4];
        float p0 = an_l[h0+0][j], p1 = an_l[h0+1][j], p2 = an_l[h0+2][j];
        a0x = fmaf(p0, zv.x, a0x); a0y = fmaf(p0, zv.y, a0y);
        a0z = fmaf(p0, zv.z, a0z); a0w = fmaf(p0, zv.w, a0w);
        a1x = fmaf(p1, zv.x, a1x); a1y = fmaf(p1, zv.y, a1y);
        a1z = fmaf(p1, zv.z, a1z); a1w = fmaf(p1, zv.w, a1w);
        a2x = fmaf(p2, zv.x, a2x); a2y = fmaf(p2, zv.y, a2y);
        a2z = fmaf(p2, zv.z, a2z); a2w = fmaf(p2, zv.w, a2w);
    }
    // fold the two j-halves together
    a0x += __shfl_xor(a0x, 32, 64); a0y += __shfl_xor(a0y, 32, 64);
    a0z += __shfl_xor(a0z, 32, 64); a0w += __shfl_xor(a0w, 32, 64);
    a1x += __shfl_xor(a1x, 32, 64); a1y += __shfl_xor(a1y, 32, 64);
    a1z += __shfl_xor(a1z, 32, 64); a1w += __shfl_xor(a1w, 32, 64);
    a2x += __shfl_xor(a2x, 32, 64); a2y += __shfl_xor(a2y, 32, 64);
    a2z += __shfl_xor(a2z, 32, 64); a2w += __shfl_xor(a2w, 32, 64);
    if (jo == 0) {
        float* crow = cat + (size_t)i*OUTIN + 576;
        float i0v = sinv[h0+0], i1v = sinv[h0+1], i2v = sinv[h0+2];
        float4 o0; o0.x = a0x*i0v; o0.y = a0y*i0v; o0.z = a0z*i0v; o0.w = a0w*i0v;
        float4 o1; o1.x = a1x*i1v; o1.y = a1y*i1v; o1.z = a1z*i1v; o1.w = a1w*i1v;
        float4 o2; o2.x = a2x*i2v; o2.y = a2y*i2v; o2.z = a2z*i2v; o2.w = a2w*i2v;
        *(float4*)(crow + (h0+0)*128 + c4*4) = o0;
        *(float4*)(crow + (h0+1)*128 + c4*4) = o1;
        *(float4*)(crow + (h0+2)*128 + c4*4) = o2;
    }
}

// ---------------- Kernel C4: o / o_pt = softmax(g) @ vallT, + rotate/norm ----------------
__global__ __launch_bounds__(256, 4) void kov(
    const float* __restrict__ vallT, const float* __restrict__ g,
    const float* __restrict__ mrow, const float* __restrict__ rot,
    const float* __restrict__ trans, float* __restrict__ cat)
{
    __shared__ float an_l[12][776];
    __shared__ float sred[12][4];
    __shared__ float sinv[12];
    __shared__ float optl[12][24];
    __shared__ float R[9], T[3];
    const int i = blockIdx.x, t = threadIdx.x, w = t >> 6, l = t & 63;
    if (t < 9) R[t] = rot[i*9 + t];
    if (t < 3) T[t] = trans[i*3 + t];

    float ps[12];
    #pragma unroll
    for (int h = 0; h < 12; ++h) ps[h] = 0.f;
    #pragma unroll
    for (int h = 0; h < 12; ++h) {
        const float mh = mrow[h*NN + i];
        const float* gr = g + ((size_t)h*NN + i)*NN;
        #pragma unroll
        for (int k = 0; k < 3; ++k) {
            int j = k*256 + t;
            float p = __expf(gr[j] - mh);
            an_l[h][j] = p;
            ps[h] += p;
        }
    }
    #pragma unroll
    for (int h = 0; h < 12; ++h) {
        float s = ps[h];
        #pragma unroll
        for (int off = 32; off >= 1; off >>= 1) s += __shfl_xor(s, off, 64);
        if (l == 0) sred[h][w] = s;
    }
    __syncthreads();
    if (t < 12) sinv[t] = 1.0f / (sred[t][0] + sred[t][1] + sred[t][2] + sred[t][3]);
    __syncthreads();

    float* crow = cat + (size_t)i*OUTIN;
    // wave w owns 120 channels [w*120, w*120+120); lane = j (float2 pairs)
    for (int cc = 0; cc < 120; ++cc) {
        const int ch = w*120 + cc;
        const int h = ch / 40, e = ch % 40;
        const float2* __restrict__ vr = (const float2*)(vallT + (size_t)ch*NN);
        const float2* __restrict__ pr = (const float2*)(&an_l[h][0]);
        float ax = 0.f, ay = 0.f;
        #pragma unroll
        for (int jc = 0; jc < 6; ++jc) {
            float2 v = vr[jc*64 + l];
            float2 p = pr[jc*64 + l];
            ax = fmaf(p.x, v.x, ax);
            ay = fmaf(p.y, v.y, ay);
        }
        float sv = ax + ay;
        #pragma unroll
        for (int off = 32; off >= 1; off >>= 1) sv += __shfl_xor(sv, off, 64);
        if (l == 0) {
            float val = sv * sinv[h];
            if (e < 16) crow[h*16 + e] = val;
            else        optl[h][e-16] = val;
        }
    }
    __syncthreads();
    if (t < 96) {
        int h = t >> 3, p = t & 7;
        float wx = optl[h][p*3+0] - T[0];
        float wy = optl[h][p*3+1] - T[1];
        float wz = optl[h][p*3+2] - T[2];
        crow[192 + 0*96 + h*8 + p] = R[0]*wx + R[3]*wy + R[6]*wz;
        crow[192 + 1*96 + h*8 + p] = R[1]*wx + R[4]*wy + R[7]*wz;
        crow[192 + 2*96 + h*8 + p] = R[2]*wx + R[5]*wy + R[8]*wz;
        crow[480 + h*8 + p] = sqrtf(fmaf(wx,wx,fmaf(wy,wy,wz*wz)) + 1e-8f);
    }
}

// ---------------- Kernel D: output projection (cat @ Wout.T + bout) ----------------
__global__ __launch_bounds__(256) void kout(
    const float* __restrict__ cat, const float* __restrict__ Wout,
    const float* __restrict__ bout, float* __restrict__ out)
{
    __shared__ float c_lds[4*528];
    int n0 = blockIdx.x * 4;
    int t = threadIdx.x;
    int o = blockIdx.y * 128 + (t & 127);
    int ng = t >> 7;   // 2 groups x 2 rows
    float b = bout[o];
    float acc[2] = {b, b};
    for (int ch = 0; ch < 4; ++ch) {
        __syncthreads();
        for (int idx = t; idx < 4*528; idx += 256)
            c_lds[idx] = cat[(size_t)(n0 + idx/528)*OUTIN + ch*528 + (idx%528)];
        __syncthreads();
        const float4* wr = reinterpret_cast<const float4*>(Wout + (size_t)o*OUTIN + ch*528);
        for (int c4 = 0; c4 < 132; ++c4) {
            float4 wv = wr[c4];
            #pragma unroll
            for (int nn = 0; nn < 2; ++nn) {
                const float* cr = &c_lds[(ng*2+nn)*528 + c4*4];
                acc[nn] = fmaf(wv.x, cr[0], acc[nn]);
                acc[nn] = fmaf(wv.y, cr[1], acc[nn]);
                acc[nn] = fmaf(wv.z, cr[2], acc[nn]);
                acc[nn] = fmaf(wv.w, cr[3], acc[nn]);
            }
        }
    }
    #pragma unroll
    for (int nn = 0; nn < 2; ++nn)
        out[(size_t)(n0 + ng*2 + nn)*384 + o] = acc[nn];
}

extern "C" void kernel_launch(void* const* d_in, const int* in_sizes, int n_in,
                              void* d_out, int out_size, void* d_ws, size_t ws_size,
                              hipStream_t stream) {
    const float* s      = (const float*)d_in[0];
    const float* z      = (const float*)d_in[1];
    const float* rot    = (const float*)d_in[2];
    const float* trans  = (const float*)d_in[3];
    const float* mask   = (const float*)d_in[4];
    const float* Wq     = (const float*)d_in[5];
    const float* bq     = (const float*)d_in[6];
    const float* Wkv    = (const float*)d_in[7];
    const float* bkv    = (const float*)d_in[8];
    const float* Wqp    = (const float*)d_in[9];
    const float* bqp    = (const float*)d_in[10];
    const float* Wkvp   = (const float*)d_in[11];
    const float* bkvp   = (const float*)d_in[12];
    const float* Wb     = (const float*)d_in[13];
    const float* bb     = (const float*)d_in[14];
    const float* head_w = (const float*)d_in[15];
    const float* Wout   = (const float*)d_in[16];
    const float* bout   = (const float*)d_in[17];
    float* out = (float*)d_out;
    float* ws  = (float*)d_ws;

    float* q     = ws;              // 147456
    float* kT    = ws + 147456;     // 147456
    float* kpT   = ws + 294912;     // 110592
    float* vallT = ws + 405504;     // 480*768 = 368640
    float* qp    = ws + 774144;     // 110592
    float* qpr   = ws + 884736;     // 110592
    float* kvpr  = ws + 995328;     // 331776
    float* mrow  = ws + 1327104;    // 9216
    float* cat   = ws + 1336320;    // 1622016
    float* lqd   = ws + 2958336;    // 7077888
    float* gbuf  = ws + 10036224;   // 7077888

    kproj<<<dim3(96, 9), 256, 0, stream>>>(s, Wq, bq, Wkv, bkv, Wqp, bqp, Wkvp, bkvp,
                                           q, kT, vallT, qpr, kvpr);
    krot<<<dim3(768), 192, 0, stream>>>(rot, trans, qpr, kvpr, qp, kpT, vallT);
    kqk<<<dim3(6, 24, 12), 256, 0, stream>>>(kT, kpT, q, qp, mask, head_w, bb, lqd);
    kbias<<<dim3(768), 256, 0, stream>>>(z, Wb, lqd, gbuf, mrow);
    kopair<<<dim3(768), 256, 0, stream>>>(z, gbuf, mrow, cat);
    kov<<<dim3(768), 256, 0, stream>>>(vallT, gbuf, mrow, rot, trans, cat);
    kout<<<dim3(192, 3), 256, 0, stream>>>(cat, Wout, bout, out);
}

// Round 6
// 436.352 us; speedup vs baseline: 1.3521x; 1.3521x over previous
//
#include <hip/hip_runtime.h>
#include <math.h>

#define NN 768
#define CS 384
#define CZ 128
#define CH 16
#define HH 12
#define PQ 4
#define PV 8
#define OUTIN 2112

#define SC_QK 0.14433756729740643f   // sqrt(1/(3*16))
#define SC_B  0.57735026918962576f   // sqrt(1/3)
#define SC_HW 0.13608276348795434f   // sqrt(2/(27*4))

// ---------------- Kernel A: input projections (s @ W.T + b) ----------------
__global__ __launch_bounds__(256) void kproj(
    const float* __restrict__ s,
    const float* __restrict__ Wq,  const float* __restrict__ bq,
    const float* __restrict__ Wkv, const float* __restrict__ bkv,
    const float* __restrict__ Wqp, const float* __restrict__ bqp,
    const float* __restrict__ Wkvp,const float* __restrict__ bkvp,
    float* __restrict__ q, float* __restrict__ kT, float* __restrict__ vallT,
    float* __restrict__ qpr, float* __restrict__ kvpr)
{
    __shared__ float s_lds[8*384];
    int n0 = blockIdx.x * 8;
    int t = threadIdx.x;
    for (int idx = t; idx < 8*384; idx += 256)
        s_lds[idx] = s[(n0 + idx/384)*384 + (idx%384)];
    __syncthreads();

    int o = blockIdx.y * 128 + (t & 127);
    int ng = t >> 7;
    const float* wrow; float bias;
    if (o < 192)      { wrow = Wq   + o*384;       bias = bq[o]; }
    else if (o < 576) { wrow = Wkv  + (o-192)*384; bias = bkv[o-192]; }
    else if (o < 720) { wrow = Wqp  + (o-576)*384; bias = bqp[o-576]; }
    else              { wrow = Wkvp + (o-720)*384; bias = bkvp[o-720]; }

    float acc[4] = {bias, bias, bias, bias};
    const float4* wr4 = reinterpret_cast<const float4*>(wrow);
    for (int c4 = 0; c4 < 96; ++c4) {
        float4 w = wr4[c4];
        #pragma unroll
        for (int nn = 0; nn < 4; ++nn) {
            const float* sr = &s_lds[(ng*4+nn)*384 + c4*4];
            acc[nn] = fmaf(w.x, sr[0], acc[nn]);
            acc[nn] = fmaf(w.y, sr[1], acc[nn]);
            acc[nn] = fmaf(w.z, sr[2], acc[nn]);
            acc[nn] = fmaf(w.w, sr[3], acc[nn]);
        }
    }
    #pragma unroll
    for (int nn = 0; nn < 4; ++nn) {
        int n = n0 + ng*4 + nn;
        float v = acc[nn];
        if (o < 192)      q[n*192 + o] = v;
        else if (o < 576) {
            int oo = o - 192, h = oo >> 5, cc = oo & 31;
            if (cc < 16) kT[(h*NN + n)*16 + cc] = v;
            else         vallT[(size_t)(h*40 + (cc-16))*NN + n] = v;
        }
        else if (o < 720) qpr[n*144 + (o-576)] = v;
        else              kvpr[n*432 + (o-720)] = v;
    }
}

// ---------------- Kernel B: apply frames (rot, trans) to points ----------------
__global__ __launch_bounds__(192) void krot(
    const float* __restrict__ rot, const float* __restrict__ trans,
    const float* __restrict__ qpr, const float* __restrict__ kvpr,
    float* __restrict__ qp, float* __restrict__ kpT, float* __restrict__ vallT)
{
    int n = blockIdx.x;
    __shared__ float R[9], T[3];
    int t = threadIdx.x;
    if (t < 9) R[t] = rot[n*9 + t];
    if (t < 3) T[t] = trans[n*3 + t];
    __syncthreads();

    const float* src = (t < 48) ? (qpr + n*144 + t*3) : (kvpr + n*432 + (t-48)*3);
    float x = src[0], y = src[1], z = src[2];
    float wx = R[0]*x + R[1]*y + R[2]*z + T[0];
    float wy = R[3]*x + R[4]*y + R[5]*z + T[1];
    float wz = R[6]*x + R[7]*y + R[8]*z + T[2];
    if (t < 48) {
        float* d = qp + n*144 + t*3;
        d[0]=wx; d[1]=wy; d[2]=wz;
    } else {
        int pi = t - 48, h = pi/12, pp = pi%12;
        if (pp < 4) {
            float* d = kpT + (h*NN+n)*12 + pp*3;
            d[0]=wx; d[1]=wy; d[2]=wz;
        } else {
            int ch = h*40 + 16 + (pp-4)*3;
            vallT[(size_t)(ch+0)*NN + n] = wx;
            vallT[(size_t)(ch+1)*NN + n] = wy;
            vallT[(size_t)(ch+2)*NN + n] = wz;
        }
    }
}

// ---------------- Kernel C1: z-independent logit part ----------------
__global__ __launch_bounds__(256) void kqk(
    const float* __restrict__ kT, const float* __restrict__ kpT,
    const float* __restrict__ q, const float* __restrict__ qp,
    const float* __restrict__ mask, const float* __restrict__ head_w,
    const float* __restrict__ bb, float* __restrict__ lqd)
{
    const int h = blockIdx.z;
    const int j0 = blockIdx.x * 128;
    const int i0 = blockIdx.y * 32;
    __shared__ float kt_l[16][132], kp_l[12][132];
    __shared__ float q_l[32][16], qp_l[32][12];
    __shared__ float mi_l[32], mj_l[128];
    const int t = threadIdx.x;
    for (int idx = t; idx < 2048; idx += 256) {
        int j = idx >> 4, c = idx & 15;
        kt_l[c][j] = kT[(size_t)(h*NN + j0 + j)*16 + c];
    }
    for (int idx = t; idx < 1536; idx += 256) {
        int j = idx / 12, e = idx - j*12;
        kp_l[e][j] = kpT[(size_t)(h*NN + j0 + j)*12 + e];
    }
    for (int idx = t; idx < 512; idx += 256) {
        int ii = idx >> 4, c = idx & 15;
        q_l[ii][c] = q[(i0+ii)*192 + h*16 + c];
    }
    for (int idx = t; idx < 384; idx += 256) {
        int ii = idx / 12, e = idx - ii*12;
        qp_l[ii][e] = qp[(i0+ii)*144 + h*12 + e];
    }
    if (t < 32)  mi_l[t] = mask[i0 + t];
    if (t < 128) mj_l[t] = mask[j0 + t];
    const float hwh = log1pf(expf(head_w[h])) * SC_HW;
    const float bbh = bb[h];
    __syncthreads();

    const int jl = t & 127, ig = t >> 7;
    const float mj = mj_l[jl];
    #pragma unroll 4
    for (int ii = 0; ii < 16; ++ii) {
        const int il = ig*16 + ii;
        float qk = 0.f;
        #pragma unroll
        for (int c = 0; c < 16; ++c) qk = fmaf(kt_l[c][jl], q_l[il][c], qk);
        float d2 = 0.f;
        #pragma unroll
        for (int e = 0; e < 12; ++e) { float d = qp_l[il][e] - kp_l[e][jl]; d2 = fmaf(d, d, d2); }
        float mt = 1e9f * (mi_l[il]*mj - 1.0f);
        float lg = fmaf(qk, SC_QK, fmaf(-0.5f*hwh, d2, bbh)) + mt;
        lqd[((size_t)h*NN + i0 + il)*NN + j0 + jl] = lg;
    }
}

// ---------------- Kernel C2: g = lqd + SC_B*(z·Wb); track row max ----------------
__global__ __launch_bounds__(256, 4) void kbias(
    const float* __restrict__ z, const float* __restrict__ Wb,
    const float* __restrict__ lqd, float* __restrict__ g_out,
    float* __restrict__ mrow)
{
    __shared__ float4 zt4[64][32];         // 32 KB, physical [j][c4 ^ (j&7)]

    const int i = blockIdx.x, t = threadIdx.x;
    const int w = t >> 6, l = t & 63, h0 = w*3;
    const int h0u = __builtin_amdgcn_readfirstlane(h0);
    const float4* __restrict__ wbh = (const float4*)(Wb + h0u*CZ);   // 96 float4: 3 head rows

    const float4* __restrict__ zg = (const float4*)(z + (size_t)i*NN*CZ);
    float4 stg[8];
    #pragma unroll
    for (int k = 0; k < 8; ++k) stg[k] = zg[k*256 + t];
    #pragma unroll
    for (int k = 0; k < 8; ++k) {
        int slot = k*256 + t, j = slot >> 5, c4 = slot & 31;
        zt4[j][c4 ^ (j & 7)] = stg[k];
    }

    float m0 = -1e30f, m1 = -1e30f, m2 = -1e30f;
    const int swl = l & 7;

    for (int tile = 0; tile < 12; ++tile) {
        __syncthreads();   // staged tile visible
        if (tile + 1 < 12) {   // T14: issue next tile's loads before compute
            #pragma unroll
            for (int k = 0; k < 8; ++k) stg[k] = zg[(tile+1)*2048 + k*256 + t];
        }
        const int j = tile*64 + l;
        float lq0 = lqd[((size_t)(h0+0)*NN + i)*NN + j];
        float lq1 = lqd[((size_t)(h0+1)*NN + i)*NN + j];
        float lq2 = lqd[((size_t)(h0+2)*NN + i)*NN + j];
        float b0 = 0.f, b1 = 0.f, b2 = 0.f;
        #pragma unroll
        for (int c4 = 0; c4 < 32; ++c4) {
            float4 zv = zt4[l][c4 ^ swl];
            float4 w0 = wbh[c4];        // wave-uniform -> s_load
            float4 w1 = wbh[32 + c4];
            float4 w2 = wbh[64 + c4];
            b0 = fmaf(zv.x,w0.x,b0); b0 = fmaf(zv.y,w0.y,b0); b0 = fmaf(zv.z,w0.z,b0); b0 = fmaf(zv.w,w0.w,b0);
            b1 = fmaf(zv.x,w1.x,b1); b1 = fmaf(zv.y,w1.y,b1); b1 = fmaf(zv.z,w1.z,b1); b1 = fmaf(zv.w,w1.w,b1);
            b2 = fmaf(zv.x,w2.x,b2); b2 = fmaf(zv.y,w2.y,b2); b2 = fmaf(zv.z,w2.z,b2); b2 = fmaf(zv.w,w2.w,b2);
        }
        float g0 = fmaf(b0, SC_B, lq0);
        float g1 = fmaf(b1, SC_B, lq1);
        float g2 = fmaf(b2, SC_B, lq2);
        g_out[((size_t)(h0+0)*NN + i)*NN + j] = g0;
        g_out[((size_t)(h0+1)*NN + i)*NN + j] = g1;
        g_out[((size_t)(h0+2)*NN + i)*NN + j] = g2;
        m0 = fmaxf(m0, g0); m1 = fmaxf(m1, g1); m2 = fmaxf(m2, g2);
        __syncthreads();   // zt4 reads done
        if (tile + 1 < 12) {
            #pragma unroll
            for (int k = 0; k < 8; ++k) {
                int slot = k*256 + t, jj = slot >> 5, c4 = slot & 31;
                zt4[jj][c4 ^ (jj & 7)] = stg[k];
            }
        }
    }

    #pragma unroll
    for (int off = 32; off >= 1; off >>= 1) {
        m0 = fmaxf(m0, __shfl_xor(m0, off, 64));
        m1 = fmaxf(m1, __shfl_xor(m1, off, 64));
        m2 = fmaxf(m2, __shfl_xor(m2, off, 64));
    }
    if (l == 0) {
        mrow[(h0+0)*NN + i] = m0;
        mrow[(h0+1)*NN + i] = m1;
        mrow[(h0+2)*NN + i] = m2;
    }
}

// ---------------- Kernel C3: merged softmax staging + o_pair + o/o_pt ----------------
__global__ __launch_bounds__(256, 4) void kfin(
    const float* __restrict__ z, const float* __restrict__ vallT,
    const float* __restrict__ g, const float* __restrict__ mrow,
    const float* __restrict__ rot, const float* __restrict__ trans,
    float* __restrict__ cat)
{
    __shared__ float an_l[12][776];
    __shared__ float sred[12][4];
    __shared__ float sinv[12];
    __shared__ float optl[12][24];
    __shared__ float R[9], T[3];
    const int i = blockIdx.x, t = threadIdx.x, w = t >> 6, l = t & 63;
    if (t < 9) R[t] = rot[i*9 + t];
    if (t < 3) T[t] = trans[i*3 + t];

    // ---- stage p = exp(g - m) for all 12 heads, block-reduce sums ----
    float ps[12];
    #pragma unroll
    for (int h = 0; h < 12; ++h) ps[h] = 0.f;
    #pragma unroll
    for (int h = 0; h < 12; ++h) {
        const float mh = mrow[h*NN + i];
        const float* gr = g + ((size_t)h*NN + i)*NN;
        #pragma unroll
        for (int k = 0; k < 3; ++k) {
            int j = k*256 + t;
            float p = __expf(gr[j] - mh);
            an_l[h][j] = p;
            ps[h] += p;
        }
    }
    #pragma unroll
    for (int h = 0; h < 12; ++h) {
        float s = ps[h];
        #pragma unroll
        for (int off = 32; off >= 1; off >>= 1) s += __shfl_xor(s, off, 64);
        if (l == 0) sred[h][w] = s;
    }
    __syncthreads();
    if (t < 12) sinv[t] = 1.0f / (sred[t][0] + sred[t][1] + sred[t][2] + sred[t][3]);
    __syncthreads();

    // ---- phase B: o_pair = p @ z (z streamed from HBM) ----
    {
        const int h0 = w*3, jo = l >> 5, c4 = l & 31;
        const float4* __restrict__ zr = (const float4*)(z + (size_t)i*NN*CZ);
        float a0x=0,a0y=0,a0z=0,a0w=0, a1x=0,a1y=0,a1z=0,a1w=0, a2x=0,a2y=0,a2z=0,a2w=0;
        #pragma unroll 4
        for (int jb = 0; jb < 384; ++jb) {
            const int j = jb*2 + jo;
            float4 zv = zr[(size_t)j*32 + c4];
            float p0 = an_l[h0+0][j], p1 = an_l[h0+1][j], p2 = an_l[h0+2][j];
            a0x = fmaf(p0, zv.x, a0x); a0y = fmaf(p0, zv.y, a0y);
            a0z = fmaf(p0, zv.z, a0z); a0w = fmaf(p0, zv.w, a0w);
            a1x = fmaf(p1, zv.x, a1x); a1y = fmaf(p1, zv.y, a1y);
            a1z = fmaf(p1, zv.z, a1z); a1w = fmaf(p1, zv.w, a1w);
            a2x = fmaf(p2, zv.x, a2x); a2y = fmaf(p2, zv.y, a2y);
            a2z = fmaf(p2, zv.z, a2z); a2w = fmaf(p2, zv.w, a2w);
        }
        a0x += __shfl_xor(a0x, 32, 64); a0y += __shfl_xor(a0y, 32, 64);
        a0z += __shfl_xor(a0z, 32, 64); a0w += __shfl_xor(a0w, 32, 64);
        a1x += __shfl_xor(a1x, 32, 64); a1y += __shfl_xor(a1y, 32, 64);
        a1z += __shfl_xor(a1z, 32, 64); a1w += __shfl_xor(a1w, 32, 64);
        a2x += __shfl_xor(a2x, 32, 64); a2y += __shfl_xor(a2y, 32, 64);
        a2z += __shfl_xor(a2z, 32, 64); a2w += __shfl_xor(a2w, 32, 64);
        if (jo == 0) {
            float* crow = cat + (size_t)i*OUTIN + 576;
            float i0v = sinv[h0+0], i1v = sinv[h0+1], i2v = sinv[h0+2];
            float4 o0; o0.x = a0x*i0v; o0.y = a0y*i0v; o0.z = a0z*i0v; o0.w = a0w*i0v;
            float4 o1; o1.x = a1x*i1v; o1.y = a1y*i1v; o1.z = a1z*i1v; o1.w = a1w*i1v;
            float4 o2; o2.x = a2x*i2v; o2.y = a2y*i2v; o2.z = a2z*i2v; o2.w = a2w*i2v;
            *(float4*)(crow + (h0+0)*128 + c4*4) = o0;
            *(float4*)(crow + (h0+1)*128 + c4*4) = o1;
            *(float4*)(crow + (h0+2)*128 + c4*4) = o2;
        }
    }

    // ---- phase C: o / o_pt = p @ vallT (L2-resident), wave-per-channel ----
    float* crow = cat + (size_t)i*OUTIN;
    for (int cc = 0; cc < 120; ++cc) {
        const int ch = w*120 + cc;
        const int h = ch / 40, e = ch % 40;
        const float2* __restrict__ vr = (const float2*)(vallT + (size_t)ch*NN);
        const float2* __restrict__ pr = (const float2*)(&an_l[h][0]);
        float ax = 0.f, ay = 0.f;
        #pragma unroll
        for (int jc = 0; jc < 6; ++jc) {
            float2 v = vr[jc*64 + l];
            float2 p = pr[jc*64 + l];
            ax = fmaf(p.x, v.x, ax);
            ay = fmaf(p.y, v.y, ay);
        }
        float sv = ax + ay;
        #pragma unroll
        for (int off = 32; off >= 1; off >>= 1) sv += __shfl_xor(sv, off, 64);
        if (l == 0) {
            float val = sv * sinv[h];
            if (e < 16) crow[h*16 + e] = val;
            else        optl[h][e-16] = val;
        }
    }
    __syncthreads();
    if (t < 96) {
        int h = t >> 3, p = t & 7;
        float wx = optl[h][p*3+0] - T[0];
        float wy = optl[h][p*3+1] - T[1];
        float wz = optl[h][p*3+2] - T[2];
        crow[192 + 0*96 + h*8 + p] = R[0]*wx + R[3]*wy + R[6]*wz;
        crow[192 + 1*96 + h*8 + p] = R[1]*wx + R[4]*wy + R[7]*wz;
        crow[192 + 2*96 + h*8 + p] = R[2]*wx + R[5]*wy + R[8]*wz;
        crow[480 + h*8 + p] = sqrtf(fmaf(wx,wx,fmaf(wy,wy,wz*wz)) + 1e-8f);
    }
}

// ---------------- Kernel D1: out partial = cat-tile @ Wout-tile^T (split-K) ----------------
// grid (24 n-tiles of 32, 6 o-tiles of 64, 6 K-splits of 352), block 256.
// LDS-staged coalesced loads; thread -> 2 n-rows x 4 o-cols (o stride 16).
__global__ __launch_bounds__(256) void koutp(
    const float* __restrict__ cat, const float* __restrict__ Wout,
    float* __restrict__ ptmp)
{
    __shared__ float ct[32][36];
    __shared__ float wt[64][36];
    const int n0 = blockIdx.x * 32, o0 = blockIdx.y * 64;
    const int k0 = blockIdx.z * 352;
    const int t = threadIdx.x;
    const int tn = (t >> 4) * 2;     // 0..30 even
    const int to = t & 15;           // o cols: to, to+16, to+32, to+48

    float a00=0,a01=0,a02=0,a03=0, a10=0,a11=0,a12=0,a13=0;

    for (int c = 0; c < 11; ++c) {
        __syncthreads();
        #pragma unroll
        for (int u = 0; u < 4; ++u) {
            int idx = u*256 + t, r = idx >> 5, cc = idx & 31;
            ct[r][cc] = cat[(size_t)(n0 + r)*OUTIN + k0 + c*32 + cc];
        }
        #pragma unroll
        for (int u = 0; u < 8; ++u) {
            int idx = u*256 + t, r = idx >> 5, cc = idx & 31;
            wt[r][cc] = Wout[(size_t)(o0 + r)*OUTIN + k0 + c*32 + cc];
        }
        __syncthreads();
        #pragma unroll
        for (int kk = 0; kk < 32; kk += 4) {
            float4 c0 = *(const float4*)&ct[tn][kk];
            float4 c1 = *(const float4*)&ct[tn+1][kk];
            float4 w0 = *(const float4*)&wt[to][kk];
            float4 w1 = *(const float4*)&wt[to+16][kk];
            float4 w2 = *(const float4*)&wt[to+32][kk];
            float4 w3 = *(const float4*)&wt[to+48][kk];
            a00 = fmaf(c0.x,w0.x,a00); a00 = fmaf(c0.y,w0.y,a00); a00 = fmaf(c0.z,w0.z,a00); a00 = fmaf(c0.w,w0.w,a00);
            a01 = fmaf(c0.x,w1.x,a01); a01 = fmaf(c0.y,w1.y,a01); a01 = fmaf(c0.z,w1.z,a01); a01 = fmaf(c0.w,w1.w,a01);
            a02 = fmaf(c0.x,w2.x,a02); a02 = fmaf(c0.y,w2.y,a02); a02 = fmaf(c0.z,w2.z,a02); a02 = fmaf(c0.w,w2.w,a02);
            a03 = fmaf(c0.x,w3.x,a03); a03 = fmaf(c0.y,w3.y,a03); a03 = fmaf(c0.z,w3.z,a03); a03 = fmaf(c0.w,w3.w,a03);
            a10 = fmaf(c1.x,w0.x,a10); a10 = fmaf(c1.y,w0.y,a10); a10 = fmaf(c1.z,w0.z,a10); a10 = fmaf(c1.w,w0.w,a10);
            a11 = fmaf(c1.x,w1.x,a11); a11 = fmaf(c1.y,w1.y,a11); a11 = fmaf(c1.z,w1.z,a11); a11 = fmaf(c1.w,w1.w,a11);
            a12 = fmaf(c1.x,w2.x,a12); a12 = fmaf(c1.y,w2.y,a12); a12 = fmaf(c1.z,w2.z,a12); a12 = fmaf(c1.w,w2.w,a12);
            a13 = fmaf(c1.x,w3.x,a13); a13 = fmaf(c1.y,w3.y,a13); a13 = fmaf(c1.z,w3.z,a13); a13 = fmaf(c1.w,w3.w,a13);
        }
    }
    float* pb = ptmp + (size_t)blockIdx.z * (NN*384);
    pb[(size_t)(n0+tn+0)*384 + o0+to+ 0] = a00;
    pb[(size_t)(n0+tn+0)*384 + o0+to+16] = a01;
    pb[(size_t)(n0+tn+0)*384 + o0+to+32] = a02;
    pb[(size_t)(n0+tn+0)*384 + o0+to+48] = a03;
    pb[(size_t)(n0+tn+1)*384 + o0+to+ 0] = a10;
    pb[(size_t)(n0+tn+1)*384 + o0+to+16] = a11;
    pb[(size_t)(n0+tn+1)*384 + o0+to+32] = a12;
    pb[(size_t)(n0+tn+1)*384 + o0+to+48] = a13;
}

// ---------------- Kernel D2: reduce split-K partials + bias ----------------
__global__ __launch_bounds__(256) void kred(
    const float* __restrict__ ptmp, const float* __restrict__ bout,
    float* __restrict__ out)
{
    int idx = blockIdx.x * 256 + threadIdx.x;   // 294912 total
    int o = idx % 384;
    float v = bout[o];
    #pragma unroll
    for (int s = 0; s < 6; ++s) v += ptmp[(size_t)s*(NN*384) + idx];
    out[idx] = v;
}

extern "C" void kernel_launch(void* const* d_in, const int* in_sizes, int n_in,
                              void* d_out, int out_size, void* d_ws, size_t ws_size,
                              hipStream_t stream) {
    const float* s      = (const float*)d_in[0];
    const float* z      = (const float*)d_in[1];
    const float* rot    = (const float*)d_in[2];
    const float* trans  = (const float*)d_in[3];
    const float* mask   = (const float*)d_in[4];
    const float* Wq     = (const float*)d_in[5];
    const float* bq     = (const float*)d_in[6];
    const float* Wkv    = (const float*)d_in[7];
    const float* bkv    = (const float*)d_in[8];
    const float* Wqp    = (const float*)d_in[9];
    const float* bqp    = (const float*)d_in[10];
    const float* Wkvp   = (const float*)d_in[11];
    const float* bkvp   = (const float*)d_in[12];
    const float* Wb     = (const float*)d_in[13];
    const float* bb     = (const float*)d_in[14];
    const float* head_w = (const float*)d_in[15];
    const float* Wout   = (const float*)d_in[16];
    const float* bout   = (const float*)d_in[17];
    float* out = (float*)d_out;
    float* ws  = (float*)d_ws;

    float* q     = ws;              // 147456
    float* kT    = ws + 147456;     // 147456
    float* kpT   = ws + 294912;     // 110592
    float* vallT = ws + 405504;     // 480*768 = 368640
    float* qp    = ws + 774144;     // 110592
    float* qpr   = ws + 884736;     // 110592
    float* kvpr  = ws + 995328;     // 331776
    float* mrow  = ws + 1327104;    // 9216
    float* cat   = ws + 1336320;    // 1622016
    float* lqd   = ws + 2958336;    // 7077888
    float* gbuf  = ws + 10036224;   // 7077888
    float* ptmp  = ws + 17114112;   // 6*768*384 = 1769472

    kproj<<<dim3(96, 9), 256, 0, stream>>>(s, Wq, bq, Wkv, bkv, Wqp, bqp, Wkvp, bkvp,
                                           q, kT, vallT, qpr, kvpr);
    krot<<<dim3(768), 192, 0, stream>>>(rot, trans, qpr, kvpr, qp, kpT, vallT);
    kqk<<<dim3(6, 24, 12), 256, 0, stream>>>(kT, kpT, q, qp, mask, head_w, bb, lqd);
    kbias<<<dim3(768), 256, 0, stream>>>(z, Wb, lqd, gbuf, mrow);
    kfin<<<dim3(768), 256, 0, stream>>>(z, vallT, gbuf, mrow, rot, trans, cat);
    koutp<<<dim3(24, 6, 6), 256, 0, stream>>>(cat, Wout, ptmp);
    kred<<<dim3(1152), 256, 0, stream>>>(ptmp, bout, out);
}